// Round 6
// baseline (401.320 us; speedup 1.0000x reference)
//
#include <hip/hip_runtime.h>
#include <hip/hip_bf16.h>

// ---------- types & helpers ----------
typedef __bf16 bf16x8 __attribute__((ext_vector_type(8)));
typedef float f32x4 __attribute__((ext_vector_type(4)));
typedef unsigned short us4 __attribute__((ext_vector_type(4)));
typedef unsigned short us8 __attribute__((ext_vector_type(8)));

__device__ __forceinline__ float bf2f(unsigned short u) {
  union { unsigned int i; float f; } v; v.i = ((unsigned int)u) << 16; return v.f;
}
__device__ __forceinline__ unsigned short f2bf(float f) {
  union { unsigned int i; float f; } v; v.f = f;
  unsigned int i = v.i;
  return (unsigned short)((i + 0x7FFFu + ((i >> 16) & 1u)) >> 16);  // RNE
}
// packed f32x2 -> bf16x2 (RNE), 1 instr; no builtin on gfx950 (T12/m240)
__device__ __forceinline__ unsigned int cvtpk_bf16(float lo, float hi) {
  unsigned int r;
  asm("v_cvt_pk_bf16_f32 %0, %1, %2" : "=v"(r) : "v"(lo), "v"(hi));
  return r;
}

// async global->LDS, 16B per lane; LDS dest = wave-uniform base + lane*16
typedef const __attribute__((address_space(1))) unsigned int* gas_ptr;
typedef __attribute__((address_space(3))) unsigned int* las_ptr;
__device__ __forceinline__ void gload_lds16(const unsigned short* g, unsigned short* l) {
  __builtin_amdgcn_global_load_lds((gas_ptr)(const void*)g, (las_ptr)(void*)l, 16, 0, 0);
}

// ---------- dtype detection: flag=1 if input is bf16, 0 if fp32 ----------
__global__ __launch_bounds__(256) void detect_k(const unsigned short* __restrict__ h,
                                                int* __restrict__ flag) {
  __shared__ int s[256];
  int cnt = 0;
  for (int i = threadIdx.x; i < 4096; i += 256) {
    unsigned short u = h[2 * i];
    int e = (u >> 7) & 0xFF;
    if ((e >= 96 && e <= 140) || u == 0) cnt++;
  }
  s[threadIdx.x] = cnt;
  __syncthreads();
  for (int o = 128; o > 0; o >>= 1) {
    if (threadIdx.x < o) s[threadIdx.x] += s[threadIdx.x + o];
    __syncthreads();
  }
  if (threadIdx.x == 0) *flag = (s[0] >= 3600) ? 1 : 0;
}

// ---------- hidden cvt (vectorized: float4 in, ushort8 out) ----------
__global__ __launch_bounds__(256) void cvt_hidden_k(const void* __restrict__ src,
                                                    unsigned short* __restrict__ dst, int n8,
                                                    const int* __restrict__ flag) {
  if (*flag) return;  // bf16 input: GEMM reads d_in[0] directly
  const float4* s = (const float4*)src;
  for (int i = blockIdx.x * 256 + threadIdx.x; i < n8; i += gridDim.x * 256) {
    float4 a = s[2 * i], b = s[2 * i + 1];
    us8 o;
    o[0] = f2bf(a.x); o[1] = f2bf(a.y); o[2] = f2bf(a.z); o[3] = f2bf(a.w);
    o[4] = f2bf(b.x); o[5] = f2bf(b.y); o[6] = f2bf(b.z); o[7] = f2bf(b.w);
    *(us8*)&dst[8 * i] = o;
  }
}

// ---------- fused weight transpose+convert (ushort4 stores) ----------
__global__ __launch_bounds__(256) void transpose_w2_k(const void* __restrict__ w_qkv,
                                                      const void* __restrict__ w_proj,
                                                      unsigned short* __restrict__ dst_qkv,
                                                      unsigned short* __restrict__ dst_proj,
                                                      const int* __restrict__ flag) {
  __shared__ unsigned short tile[32][33];
  const int f = *flag;
  int bid = blockIdx.x;
  const void* src;
  unsigned short* dst;
  int R = 2048, C, cx, cy;
  if (bid < 12288) {
    src = w_qkv; dst = dst_qkv; C = 6144; cx = bid % 192; cy = bid / 192;
  } else {
    bid -= 12288;
    src = w_proj; dst = dst_proj; C = 2048; cx = bid % 64; cy = bid / 64;
  }
  const int x = threadIdx.x & 31;
  const int y = threadIdx.x >> 5;  // 0..7
  const int r0 = cy * 32, c0 = cx * 32;
#pragma unroll
  for (int i = 0; i < 4; i++) {
    size_t idx = (size_t)(r0 + y + 8 * i) * C + c0 + x;
    tile[y + 8 * i][x] = f ? ((const unsigned short*)src)[idx]
                           : f2bf(((const float*)src)[idx]);
  }
  __syncthreads();
  const int orow = threadIdx.x >> 3;        // 0..31
  const int oc = (threadIdx.x & 7) * 4;     // 0,4,..,28
  us4 v;
  v[0] = tile[oc][orow]; v[1] = tile[oc + 1][orow];
  v[2] = tile[oc + 2][orow]; v[3] = tile[oc + 3][orow];
  *(us4*)&dst[(size_t)(c0 + orow) * R + r0 + oc] = v;
}

// ============================================================================
// QKV GEMM: 256x192 tile, BK=64, 8 waves (4M x 2N, 64x96 each), 3 phases/K-tile.
// Round-3 verified schedule (102-104 us). Round-6: V columns (n >= 4096) are
// written DIRECTLY TRANSPOSED into Vt (us4 of 4 consecutive s) and skipped in
// the QKV buffer -> transpose_v_k kernel deleted. The 4096 boundary is
// 16-aligned so each cf-block of 16 cols is uniformly K-side or V-side.
// ============================================================================
__global__ __launch_bounds__(512, 2) void gemm_qkv_k(const unsigned short* __restrict__ A_bf,
                                                     const unsigned short* __restrict__ A_cvt,
                                                     const unsigned short* __restrict__ Bt,
                                                     const void* __restrict__ bias,
                                                     unsigned short* __restrict__ Cout,
                                                     unsigned short* __restrict__ Vt,
                                                     int M, int N, int K,
                                                     const int* __restrict__ flag) {
  __shared__ __attribute__((aligned(16))) unsigned short As[2][256][64];
  __shared__ __attribute__((aligned(16))) unsigned short Bs[2][192][64];
  const int f = *flag;
  const unsigned short* Ap = f ? A_bf : A_cvt;
  const int t = threadIdx.x;
  const int wave = t >> 6, lane = t & 63;
  const int col = lane & 15, quad = lane >> 4;
  const int wm = wave >> 1, wn = wave & 1;  // 4M x 2N; per-wave 64 rows x 96 cols

  // bijective XCD swizzle (nwg = 512, %8 == 0)
  const int nbx = N / 192;
  int wgid = blockIdx.y * nbx + blockIdx.x;
  const int nwg = (M >> 8) * nbx;
  if ((nwg & 7) == 0) {
    const int cpx = nwg >> 3;
    wgid = (wgid & 7) * cpx + (wgid >> 3);
  }
  const int n0 = (wgid % nbx) * 192;
  const int m0 = (wgid / nbx) << 8;

  const int srow = lane >> 3;              // 0..7 within an 8-row group
  const int sx = ((lane & 7) ^ srow) * 8;  // pre-swizzled global k-chunk (shorts)
  const int rsw = col & 7;                 // read-side swizzle key

  const unsigned short* pA = Ap + (size_t)(m0 + wave * 8 + srow) * K + sx;
  const unsigned short* pB = Bt + (size_t)(n0 + wave * 8 + srow) * K + sx;
  const int NT = K >> 6;  // 32

#define STAGE_A(d, q, kt) \
  gload_lds16(pA + (size_t)((q) * 64) * K + (size_t)(kt) * 64, &As[(d)][(q) * 64 + wave * 8][0])
#define STAGE_B(d, q, kt) \
  gload_lds16(pB + (size_t)((q) * 64) * K + (size_t)(kt) * 64, &Bs[(d)][(q) * 64 + wave * 8][0])
#define LDA(d, rf, kk) \
  (*(const bf16x8*)&As[(d)][wm * 64 + (rf) * 16 + col][((((kk) << 2) | quad) ^ rsw) * 8])
#define LDB(d, cf, kk) \
  (*(const bf16x8*)&Bs[(d)][wn * 96 + (cf) * 16 + col][((((kk) << 2) | quad) ^ rsw) * 8])

  const f32x4 fzero = {0.f, 0.f, 0.f, 0.f};
  f32x4 acc[4][6];
#pragma unroll
  for (int i = 0; i < 4; i++)
#pragma unroll
    for (int j = 0; j < 6; j++) acc[i][j] = fzero;

  bf16x8 aA[4][2], aB[4][2];  // ping-pong A fragment sets (static-indexed)

  STAGE_A(0, 0, 0); STAGE_A(0, 1, 0); STAGE_A(0, 2, 0); STAGE_A(0, 3, 0);
  STAGE_B(0, 0, 0); STAGE_B(0, 1, 0); STAGE_B(0, 2, 0);
  STAGE_A(1, 0, 1); STAGE_A(1, 1, 1); STAGE_A(1, 2, 1); STAGE_A(1, 3, 1);
  asm volatile("s_waitcnt vmcnt(4)" ::: "memory");
  __builtin_amdgcn_sched_barrier(0);
  __builtin_amdgcn_s_barrier();

#define BODY(D, U, FIRST, SB, SA, VM2, VM3, PRER, ACUR, ANXT)                              \
  {                                                                                        \
    if (FIRST) {                                                                           \
      _Pragma("unroll") for (int rf = 0; rf < 4; rf++) {                                   \
        ACUR[rf][0] = LDA(D, rf, 0);                                                       \
        ACUR[rf][1] = LDA(D, rf, 1);                                                       \
      }                                                                                    \
    }                                                                                      \
    bf16x8 b01[2][2];                                                                      \
    _Pragma("unroll") for (int c = 0; c < 2; c++) {                                        \
      b01[c][0] = LDB(D, c, 0);                                                            \
      b01[c][1] = LDB(D, c, 1);                                                            \
    }                                                                                      \
    if (SB) { STAGE_B((D) ^ 1, 0, (U) + 1); STAGE_B((D) ^ 1, 1, (U) + 1); }                \
    __builtin_amdgcn_s_barrier();                                                          \
    asm volatile("s_waitcnt lgkmcnt(0)" ::: "memory");                                     \
    __builtin_amdgcn_sched_barrier(0);                                                     \
    __builtin_amdgcn_s_setprio(1);                                                         \
    _Pragma("unroll") for (int rf = 0; rf < 4; rf++)                                       \
      _Pragma("unroll") for (int c = 0; c < 2; c++) {                                      \
        acc[rf][c] = __builtin_amdgcn_mfma_f32_16x16x32_bf16(ACUR[rf][0], b01[c][0], acc[rf][c], 0, 0, 0); \
        acc[rf][c] = __builtin_amdgcn_mfma_f32_16x16x32_bf16(ACUR[rf][1], b01[c][1], acc[rf][c], 0, 0, 0); \
      }                                                                                    \
    __builtin_amdgcn_s_setprio(0);                                                         \
    bf16x8 b23[2][2];                                                                      \
    _Pragma("unroll") for (int c = 0; c < 2; c++) {                                        \
      b23[c][0] = LDB(D, (c) + 2, 0);                                                      \
      b23[c][1] = LDB(D, (c) + 2, 1);                                                      \
    }                                                                                      \
    if (SB) STAGE_B((D) ^ 1, 2, (U) + 1);                                                  \
    if (SA) { STAGE_A(D, 0, (U) + 2); STAGE_A(D, 1, (U) + 2); }                            \
    asm volatile("s_waitcnt " VM2 ::: "memory");                                           \
    __builtin_amdgcn_s_barrier();                                                          \
    asm volatile("s_waitcnt lgkmcnt(0)" ::: "memory");                                     \
    __builtin_amdgcn_sched_barrier(0);                                                     \
    __builtin_amdgcn_s_setprio(1);                                                         \
    _Pragma("unroll") for (int rf = 0; rf < 4; rf++)                                       \
      _Pragma("unroll") for (int c = 0; c < 2; c++) {                                      \
        acc[rf][(c) + 2] = __builtin_amdgcn_mfma_f32_16x16x32_bf16(ACUR[rf][0], b23[c][0], acc[rf][(c) + 2], 0, 0, 0); \
        acc[rf][(c) + 2] = __builtin_amdgcn_mfma_f32_16x16x32_bf16(ACUR[rf][1], b23[c][1], acc[rf][(c) + 2], 0, 0, 0); \
      }                                                                                    \
    __builtin_amdgcn_s_setprio(0);                                                         \
    bf16x8 b45[2][2];                                                                      \
    _Pragma("unroll") for (int c = 0; c < 2; c++) {                                        \
      b45[c][0] = LDB(D, (c) + 4, 0);                                                      \
      b45[c][1] = LDB(D, (c) + 4, 1);                                                      \
    }                                                                                      \
    __builtin_amdgcn_sched_barrier(0); /* pin: b45 issued before pre-reads (lgkm count) */ \
    if (PRER) {                                                                            \
      _Pragma("unroll") for (int rf = 0; rf < 4; rf++) {                                   \
        ANXT[rf][0] = LDA((D) ^ 1, rf, 0);                                                 \
        ANXT[rf][1] = LDA((D) ^ 1, rf, 1);                                                 \
      }                                                                                    \
    }                                                                                      \
    if (SA) { STAGE_A(D, 2, (U) + 2); STAGE_A(D, 3, (U) + 2); }                            \
    asm volatile("s_waitcnt " VM3 ::: "memory");                                           \
    __builtin_amdgcn_s_barrier();                                                          \
    if (PRER) asm volatile("s_waitcnt lgkmcnt(8)" ::: "memory");                           \
    else      asm volatile("s_waitcnt lgkmcnt(0)" ::: "memory");                           \
    __builtin_amdgcn_sched_barrier(0);                                                     \
    __builtin_amdgcn_s_setprio(1);                                                         \
    _Pragma("unroll") for (int rf = 0; rf < 4; rf++)                                       \
      _Pragma("unroll") for (int c = 0; c < 2; c++) {                                      \
        acc[rf][(c) + 4] = __builtin_amdgcn_mfma_f32_16x16x32_bf16(ACUR[rf][0], b45[c][0], acc[rf][(c) + 4], 0, 0, 0); \
        acc[rf][(c) + 4] = __builtin_amdgcn_mfma_f32_16x16x32_bf16(ACUR[rf][1], b45[c][1], acc[rf][(c) + 4], 0, 0, 0); \
      }                                                                                    \
    __builtin_amdgcn_s_setprio(0);                                                         \
  }

  BODY(0, 0, 1, 1, 1, "vmcnt(5)", "vmcnt(4)", 1, aA, aB)
  BODY(1, 1, 0, 1, 1, "vmcnt(5)", "vmcnt(4)", 1, aB, aA)
  for (int u2 = 2; u2 + 3 < NT; u2 += 2) {
    BODY(0, u2, 0, 1, 1, "vmcnt(5)", "vmcnt(4)", 1, aA, aB)
    BODY(1, u2 + 1, 0, 1, 1, "vmcnt(5)", "vmcnt(4)", 1, aB, aA)
  }
  BODY(0, NT - 2, 0, 1, 0, "vmcnt(3)", "vmcnt(0)", 1, aA, aB)
  BODY(1, NT - 1, 0, 0, 0, "vmcnt(0)", "vmcnt(0)", 0, aB, aA)

#undef BODY
#undef STAGE_A
#undef STAGE_B
#undef LDA
#undef LDB

  // epilogue: Q/K -> Cout (row-major); V (n>=4096) -> Vt transposed.
  const int vb = m0 >> 11;        // batch (m0 multiple of 256: never straddles)
  const int vs = (m0 & 2047) + wm * 64 + quad * 4;
#pragma unroll
  for (int cf = 0; cf < 6; cf++) {
    int n = n0 + wn * 96 + cf * 16 + col;
    float bv = f ? bf2f(((const unsigned short*)bias)[n]) : ((const float*)bias)[n];
    if (n < 4096) {
#pragma unroll
      for (int rf = 0; rf < 4; rf++)
#pragma unroll
        for (int r = 0; r < 4; r++) {
          int m = m0 + wm * 64 + rf * 16 + quad * 4 + r;
          Cout[(size_t)m * N + n] = f2bf(acc[rf][cf][r] + bv);
        }
    } else {
      size_t vrow = ((size_t)(vb * 2048 + (n - 4096))) * 2048;
#pragma unroll
      for (int rf = 0; rf < 4; rf++) {
        us4 vv;
#pragma unroll
        for (int r = 0; r < 4; r++) vv[r] = f2bf(acc[rf][cf][r] + bv);
        *(us4*)&Vt[vrow + vs + rf * 16] = vv;
      }
    }
  }
}

// ============================================================================
// proj GEMM, 256x128 tile, BK=64, 8 waves, 2 phases/K-tile, grid 256 = 1 round.
// (unchanged)
// ============================================================================
__global__ __launch_bounds__(512, 2) void gemm_proj_k(const unsigned short* __restrict__ A,
                                                      const unsigned short* __restrict__ Bt,
                                                      const void* __restrict__ bias,
                                                      void* __restrict__ Cout,
                                                      int M, int N, int K,
                                                      const int* __restrict__ flag) {
  __shared__ __attribute__((aligned(16))) unsigned short As[2][256][64];
  __shared__ __attribute__((aligned(16))) unsigned short Bs[2][128][64];
  const int f = *flag;
  const int t = threadIdx.x;
  const int wave = t >> 6, lane = t & 63;
  const int col = lane & 15, quad = lane >> 4;
  const int wm = wave >> 1, wn = wave & 1;  // 4M x 2N; per-wave 64 x 64

  const int nbx = N >> 7;
  int wgid = blockIdx.y * nbx + blockIdx.x;
  const int nwg = (M >> 8) * nbx;
  if ((nwg & 7) == 0) {
    const int cpx = nwg >> 3;
    wgid = (wgid & 7) * cpx + (wgid >> 3);
  }
  const int n0 = (wgid % nbx) << 7;
  const int m0 = (wgid / nbx) << 8;

  const int srow = lane >> 3;
  const int sx = ((lane & 7) ^ srow) * 8;
  const int rsw = col & 7;

  const unsigned short* pA = A + (size_t)(m0 + wave * 8 + srow) * K + sx;
  const unsigned short* pB = Bt + (size_t)(n0 + wave * 8 + srow) * K + sx;
  const int NT = K >> 6;  // 32

#define STAGE_A(d, q, kt) \
  gload_lds16(pA + (size_t)((q) * 64) * K + (size_t)(kt) * 64, &As[(d)][(q) * 64 + wave * 8][0])
#define STAGE_B(d, q, kt) \
  gload_lds16(pB + (size_t)((q) * 64) * K + (size_t)(kt) * 64, &Bs[(d)][(q) * 64 + wave * 8][0])
#define LDA(d, rf, kk) \
  (*(const bf16x8*)&As[(d)][wm * 64 + (rf) * 16 + col][((((kk) << 2) | quad) ^ rsw) * 8])
#define LDB(d, cf, kk) \
  (*(const bf16x8*)&Bs[(d)][wn * 64 + (cf) * 16 + col][((((kk) << 2) | quad) ^ rsw) * 8])

  const f32x4 fzero = {0.f, 0.f, 0.f, 0.f};
  f32x4 acc[4][4];
#pragma unroll
  for (int i = 0; i < 4; i++)
#pragma unroll
    for (int j = 0; j < 4; j++) acc[i][j] = fzero;

  bf16x8 aA[4][2], aB[4][2];

  STAGE_A(0, 0, 0); STAGE_A(0, 1, 0); STAGE_A(0, 2, 0); STAGE_A(0, 3, 0);
  STAGE_B(0, 0, 0); STAGE_B(0, 1, 0);
  STAGE_A(1, 0, 1); STAGE_A(1, 1, 1); STAGE_A(1, 2, 1); STAGE_A(1, 3, 1);
  asm volatile("s_waitcnt vmcnt(4)" ::: "memory");
  __builtin_amdgcn_sched_barrier(0);
  __builtin_amdgcn_s_barrier();

#define BODY(D, U, FIRST, SB, SA, VM1, VM2, PRER, ACUR, ANXT)                              \
  {                                                                                        \
    if (FIRST) {                                                                           \
      _Pragma("unroll") for (int rf = 0; rf < 4; rf++) {                                   \
        ACUR[rf][0] = LDA(D, rf, 0);                                                       \
        ACUR[rf][1] = LDA(D, rf, 1);                                                       \
      }                                                                                    \
    }                                                                                      \
    bf16x8 b01[2][2];                                                                      \
    _Pragma("unroll") for (int c = 0; c < 2; c++) {                                        \
      b01[c][0] = LDB(D, c, 0);                                                            \
      b01[c][1] = LDB(D, c, 1);                                                            \
    }                                                                                      \
    if (SB) { STAGE_B((D) ^ 1, 0, (U) + 1); STAGE_B((D) ^ 1, 1, (U) + 1); }                \
    asm volatile("s_waitcnt " VM1 ::: "memory");                                           \
    __builtin_amdgcn_s_barrier();                                                          \
    asm volatile("s_waitcnt lgkmcnt(0)" ::: "memory");                                     \
    __builtin_amdgcn_sched_barrier(0);                                                     \
    __builtin_amdgcn_s_setprio(1);                                                         \
    _Pragma("unroll") for (int rf = 0; rf < 4; rf++)                                       \
      _Pragma("unroll") for (int c = 0; c < 2; c++) {                                      \
        acc[rf][c] = __builtin_amdgcn_mfma_f32_16x16x32_bf16(ACUR[rf][0], b01[c][0], acc[rf][c], 0, 0, 0); \
        acc[rf][c] = __builtin_amdgcn_mfma_f32_16x16x32_bf16(ACUR[rf][1], b01[c][1], acc[rf][c], 0, 0, 0); \
      }                                                                                    \
    __builtin_amdgcn_s_setprio(0);                                                         \
    bf16x8 b23[2][2];                                                                      \
    _Pragma("unroll") for (int c = 0; c < 2; c++) {                                        \
      b23[c][0] = LDB(D, (c) + 2, 0);                                                      \
      b23[c][1] = LDB(D, (c) + 2, 1);                                                      \
    }                                                                                      \
    __builtin_amdgcn_sched_barrier(0); /* pin: b23 before pre-reads */                     \
    if (PRER) {                                                                            \
      _Pragma("unroll") for (int rf = 0; rf < 4; rf++) {                                   \
        ANXT[rf][0] = LDA((D) ^ 1, rf, 0);                                                 \
        ANXT[rf][1] = LDA((D) ^ 1, rf, 1);                                                 \
      }                                                                                    \
    }                                                                                      \
    if (SA) { STAGE_A(D, 0, (U) + 2); STAGE_A(D, 1, (U) + 2);                              \
              STAGE_A(D, 2, (U) + 2); STAGE_A(D, 3, (U) + 2); }                            \
    asm volatile("s_waitcnt " VM2 ::: "memory");                                           \
    __builtin_amdgcn_s_barrier();                                                          \
    if (PRER) asm volatile("s_waitcnt lgkmcnt(8)" ::: "memory");                           \
    else      asm volatile("s_waitcnt lgkmcnt(0)" ::: "memory");                           \
    __builtin_amdgcn_sched_barrier(0);                                                     \
    __builtin_amdgcn_s_setprio(1);                                                         \
    _Pragma("unroll") for (int rf = 0; rf < 4; rf++)                                       \
      _Pragma("unroll") for (int c = 0; c < 2; c++) {                                      \
        acc[rf][(c) + 2] = __builtin_amdgcn_mfma_f32_16x16x32_bf16(ACUR[rf][0], b23[c][0], acc[rf][(c) + 2], 0, 0, 0); \
        acc[rf][(c) + 2] = __builtin_amdgcn_mfma_f32_16x16x32_bf16(ACUR[rf][1], b23[c][1], acc[rf][(c) + 2], 0, 0, 0); \
      }                                                                                    \
    __builtin_amdgcn_s_setprio(0);                                                         \
  }

  BODY(0, 0, 1, 1, 1, "vmcnt(2)", "vmcnt(4)", 1, aA, aB)
  BODY(1, 1, 0, 1, 1, "vmcnt(2)", "vmcnt(4)", 1, aB, aA)
  for (int u2 = 2; u2 + 3 < NT; u2 += 2) {
    BODY(0, u2, 0, 1, 1, "vmcnt(2)", "vmcnt(4)", 1, aA, aB)
    BODY(1, u2 + 1, 0, 1, 1, "vmcnt(2)", "vmcnt(4)", 1, aB, aA)
  }
  BODY(0, NT - 2, 0, 1, 0, "vmcnt(2)", "vmcnt(0)", 1, aA, aB)
  BODY(1, NT - 1, 0, 0, 0, "vmcnt(0)", "vmcnt(0)", 0, aB, aA)

#undef BODY
#undef STAGE_A
#undef STAGE_B
#undef LDA
#undef LDB

  const int f32o = (f == 0);
#pragma unroll
  for (int cf = 0; cf < 4; cf++) {
    int n = n0 + wn * 64 + cf * 16 + col;
    float bv = f ? bf2f(((const unsigned short*)bias)[n]) : ((const float*)bias)[n];
#pragma unroll
    for (int rf = 0; rf < 4; rf++)
#pragma unroll
      for (int r = 0; r < 4; r++) {
        int m = m0 + wm * 64 + rf * 16 + quad * 4 + r;
        float v = acc[rf][cf][r] + bv;
        if (f32o) ((float*)Cout)[(size_t)m * N + n] = v;
        else      ((unsigned short*)Cout)[(size_t)m * N + n] = f2bf(v);
      }
  }
}

// ---------- flash attention (causal), paired q-tiles ----------
// Round-6: (a) XCD-locality remap: blocks p with p&7 == x all land on XCD x
// (round-robin dispatch); each XCD owns 4 (b,h) pairs -> K/V working set
// 4 MB = L2-sized (was ~32 MB -> thrash). (b) 2-deep register prefetch:
// loads for kt+2 issued at iter kt; regs written to LDS one iter after load
// -> compiler emits counted vmcnt (not 0) before ds_write; raw s_barrier
// (NOT __syncthreads, which would drain vmcnt and kill the pipeline).
// Race ledger: iter kt reads Ks/Vs[kt&1], writes [kt&1 ^1] (data for kt+1);
// that buffer's last reads were iter kt-1, separated by iter-(kt-1) barrier.
// Ps wave-private (program order + compiler lgkm).
#define ATT_SC2 0.1275174367076458f  // (1/sqrt(128)) * log2(e)
__global__ __launch_bounds__(256) void attn_k(const unsigned short* __restrict__ qkv,
                                              const unsigned short* __restrict__ Vt,
                                              unsigned short* __restrict__ O) {
  __shared__ __attribute__((aligned(16))) unsigned short Ks[2][64][136];  // [key][d]
  __shared__ __attribute__((aligned(16))) unsigned short Vs[2][128][72];  // V^T: [d][key]
  __shared__ __attribute__((aligned(16))) unsigned short Ps[4][16][72];
  const int t = threadIdx.x;
  const int wave = t >> 6, lane = t & 63;
  const int col = lane & 15, quad = lane >> 4;

  // XCD-locality remap (bijective on [0,512))
  const int p = (int)(blockIdx.x + 16 * blockIdx.y + (blockIdx.z << 8));
  const int j = p >> 3;
  const int g = (p & 7) * 4 + (j >> 4);   // (b,h) group 0..31
  const int qx = j & 15;                   // q-block pair index 0..15
  const int b = g >> 4, h = g & 15;

  const size_t base = (size_t)b * 2048 * 6144;
  const size_t vbase = ((size_t)(b * 16 + h)) * 128 * 2048;
  const int hcol = h * 128;

  const int kr = t >> 2;
  const int kc = (t & 3) * 8;
  const int vr = t >> 1;
  const int vc = (t & 1) * 32;

  const f32x4 fzero = {0.f, 0.f, 0.f, 0.f};

#define LOADR(KR, VR, ktn)                                                      \
  do {                                                                          \
    size_t grow = base + (size_t)((ktn) * 64 + kr) * 6144 + 2048 + hcol;        \
    _Pragma("unroll") for (int pq = 0; pq < 4; pq++)                            \
      KR[pq] = *(const bf16x8*)&qkv[grow + kc + pq * 32];                       \
    size_t vrow = vbase + (size_t)vr * 2048 + (ktn) * 64;                       \
    _Pragma("unroll") for (int c = 0; c < 4; c++)                               \
      VR[c] = *(const bf16x8*)&Vt[vrow + vc + c * 8];                           \
  } while (0)

#define ITER(KT, DBF, CK, CV, NK, NV)                                           \
  {                                                                             \
    if ((KT) + 2 <= qt) LOADR(NK, NV, (KT) + 2);                                \
    f32x4 sc[4];                                                                \
    __builtin_amdgcn_s_setprio(1);                                              \
    _Pragma("unroll") for (int nb = 0; nb < 4; nb++) {                          \
      f32x4 s = fzero;                                                          \
      _Pragma("unroll") for (int ks = 0; ks < 4; ks++) {                        \
        bf16x8 kf = *(const bf16x8*)&Ks[DBF][nb * 16 + col][ks * 32 + quad * 8];\
        s = __builtin_amdgcn_mfma_f32_16x16x32_bf16(qf[ks], kf, s, 0, 0, 0);    \
      }                                                                         \
      sc[nb] = s;                                                               \
    }                                                                           \
    __builtin_amdgcn_s_setprio(0);                                              \
    const bool diag = ((KT) == qt);                                             \
    _Pragma("unroll") for (int nb = 0; nb < 4; nb++) {                          \
      int kl = nb * 16 + col;                                                   \
      float p0, p1, p2, p3;                                                     \
      {                                                                         \
        float s0 = sc[nb][0], s1 = sc[nb][1], s2 = sc[nb][2], s3 = sc[nb][3];   \
        if (diag) {                                                             \
          int qrow = wave * 16 + quad * 4;                                      \
          if (kl > qrow + 0) s0 = -1e30f;                                       \
          if (kl > qrow + 1) s1 = -1e30f;                                       \
          if (kl > qrow + 2) s2 = -1e30f;                                       \
          if (kl > qrow + 3) s3 = -1e30f;                                       \
        }                                                                       \
        p0 = exp2f(s0 * ATT_SC2); p1 = exp2f(s1 * ATT_SC2);                     \
        p2 = exp2f(s2 * ATT_SC2); p3 = exp2f(s3 * ATT_SC2);                     \
        l_i[0] += p0; l_i[1] += p1; l_i[2] += p2; l_i[3] += p3;                 \
      }                                                                         \
      unsigned int w01 = cvtpk_bf16(p0, p1);                                    \
      unsigned int w23 = cvtpk_bf16(p2, p3);                                    \
      unsigned short* pb = &Ps[wave][quad * 4][nb * 16 + col];                  \
      pb[0]   = (unsigned short)w01;                                            \
      pb[72]  = (unsigned short)(w01 >> 16);                                    \
      pb[144] = (unsigned short)w23;                                            \
      pb[216] = (unsigned short)(w23 >> 16);                                    \
    }                                                                           \
    bf16x8 pfr[2];                                                              \
    _Pragma("unroll") for (int ks2 = 0; ks2 < 2; ks2++)                         \
      pfr[ks2] = *(const bf16x8*)&Ps[wave][col][ks2 * 32 + quad * 8];           \
    __builtin_amdgcn_s_setprio(1);                                              \
    _Pragma("unroll") for (int nbo = 0; nbo < 8; nbo++)                         \
      _Pragma("unroll") for (int ks2 = 0; ks2 < 2; ks2++) {                     \
        bf16x8 vf = *(const bf16x8*)&Vs[DBF][nbo * 16 + col][ks2 * 32 + quad * 8]; \
        o[nbo] = __builtin_amdgcn_mfma_f32_16x16x32_bf16(pfr[ks2], vf, o[nbo], 0, 0, 0); \
      }                                                                         \
    __builtin_amdgcn_s_setprio(0);                                              \
    if ((KT) + 1 <= qt) {                                                       \
      _Pragma("unroll") for (int pq = 0; pq < 4; pq++)                          \
        *(bf16x8*)&Ks[(DBF) ^ 1][kr][kc + pq * 32] = CK[pq];                    \
      _Pragma("unroll") for (int c = 0; c < 4; c++)                             \
        *(bf16x8*)&Vs[(DBF) ^ 1][vr][vc + c * 8] = CV[c];                       \
    }                                                                           \
    asm volatile("s_waitcnt lgkmcnt(0)" ::: "memory");                          \
    __builtin_amdgcn_sched_barrier(0);                                          \
    __builtin_amdgcn_s_barrier();                                               \
    asm volatile("" ::: "memory");                                              \
  }

  for (int pass = 0; pass < 2; pass++) {
    const int qt = pass ? qx : 31 - qx;

    bf16x8 qf[4];
    {
      size_t qrow = base + (size_t)(qt * 64 + wave * 16 + col) * 6144 + hcol;
#pragma unroll
      for (int ks = 0; ks < 4; ks++)
        qf[ks] = *(const bf16x8*)&qkv[qrow + ks * 32 + quad * 8];
    }

    f32x4 o[8];
#pragma unroll
    for (int i = 0; i < 8; i++) o[i] = fzero;
    float l_i[4] = {0.f, 0.f, 0.f, 0.f};

    __syncthreads();  // guard LDS (both buffers) vs previous pass readers
    {
      size_t grow = base + (size_t)kr * 6144 + 2048 + hcol;
#pragma unroll
      for (int pq = 0; pq < 4; pq++)
        *(bf16x8*)&Ks[0][kr][kc + pq * 32] = *(const bf16x8*)&qkv[grow + kc + pq * 32];
      size_t vrow = vbase + (size_t)vr * 2048;
#pragma unroll
      for (int c = 0; c < 4; c++)
        *(bf16x8*)&Vs[0][vr][vc + c * 8] = *(const bf16x8*)&Vt[vrow + vc + c * 8];
    }
    __syncthreads();

    bf16x8 kA[4], vA[4], kB[4], vB[4];
    if (qt >= 1) LOADR(kA, vA, 1);

    for (int kt = 0; kt <= qt;) {
      ITER(kt, 0, kA, vA, kB, vB);
      kt++;
      if (kt > qt) break;
      ITER(kt, 1, kB, vB, kA, vA);
      kt++;
    }

#pragma unroll
    for (int r = 0; r < 4; r++) {
#pragma unroll
      for (int off = 1; off < 16; off <<= 1)
        l_i[r] += __shfl_xor(l_i[r], off, 64);
      l_i[r] = 1.0f / l_i[r];
    }

#pragma unroll
    for (int nbo = 0; nbo < 8; nbo++)
#pragma unroll
      for (int r = 0; r < 4; r++) {
        int m = qt * 64 + wave * 16 + quad * 4 + r;
        O[((size_t)b * 2048 + m) * 2048 + hcol + nbo * 16 + col] = f2bf(o[nbo][r] * l_i[r]);
      }
  }
#undef ITER
#undef LOADR
}

// ---------- launch ----------
extern "C" void kernel_launch(void* const* d_in, const int* in_sizes, int n_in,
                              void* d_out, int out_size, void* d_ws, size_t ws_size,
                              hipStream_t stream) {
  (void)in_sizes; (void)n_in; (void)out_size; (void)ws_size;
  int* flag = (int*)d_ws;
  unsigned short* wsu = (unsigned short*)d_ws + 128;
  unsigned short* Wt_qkv    = wsu;                                  // 6144*2048
  unsigned short* Wt_proj   = Wt_qkv + (size_t)6144 * 2048;         // 2048*2048
  unsigned short* QKV       = Wt_proj + (size_t)2048 * 2048;        // 4096*6144
  unsigned short* hidden_bf = QKV + (size_t)4096 * 6144;            // 4096*2048
  unsigned short* Obuf      = Wt_qkv;     // alias: dead after QKV gemm
  unsigned short* Vt        = hidden_bf + (size_t)4096 * 2048;      // 32*128*2048

  detect_k<<<1, 256, 0, stream>>>((const unsigned short*)d_in[0], flag);
  cvt_hidden_k<<<2048, 256, 0, stream>>>(d_in[0], hidden_bf, (4096 * 2048) / 8, flag);
  transpose_w2_k<<<16384, 256, 0, stream>>>(d_in[1], d_in[3], Wt_qkv, Wt_proj, flag);
  // QKV GEMM: 256x192 tile, grid 32x16 = 512 blocks; V written direct to Vt
  gemm_qkv_k<<<dim3(32, 16), 512, 0, stream>>>((const unsigned short*)d_in[0], hidden_bf,
                                               Wt_qkv, d_in[2], QKV, Vt,
                                               4096, 6144, 2048, flag);
  attn_k<<<dim3(16, 16, 2), 256, 0, stream>>>(QKV, Vt, Obuf);
  // proj GEMM: 256x128 tile, grid 16x16 = 256 blocks = exactly 1 round
  gemm_proj_k<<<dim3(16, 16), 512, 0, stream>>>(Obuf, Wt_proj, d_in[4], d_out,
                                                4096, 2048, 2048, flag);
}

// Round 7
// 375.620 us; speedup vs baseline: 1.0684x; 1.0684x over previous
//
#include <hip/hip_runtime.h>
#include <hip/hip_bf16.h>

// ---------- types & helpers ----------
typedef __bf16 bf16x8 __attribute__((ext_vector_type(8)));
typedef float f32x4 __attribute__((ext_vector_type(4)));
typedef unsigned short us4 __attribute__((ext_vector_type(4)));
typedef unsigned short us8 __attribute__((ext_vector_type(8)));

__device__ __forceinline__ float bf2f(unsigned short u) {
  union { unsigned int i; float f; } v; v.i = ((unsigned int)u) << 16; return v.f;
}
__device__ __forceinline__ unsigned short f2bf(float f) {
  union { unsigned int i; float f; } v; v.f = f;
  unsigned int i = v.i;
  return (unsigned short)((i + 0x7FFFu + ((i >> 16) & 1u)) >> 16);  // RNE
}
// packed f32x2 -> bf16x2 (RNE), 1 instr; no builtin on gfx950 (T12/m240)
__device__ __forceinline__ unsigned int cvtpk_bf16(float lo, float hi) {
  unsigned int r;
  asm("v_cvt_pk_bf16_f32 %0, %1, %2" : "=v"(r) : "v"(lo), "v"(hi));
  return r;
}

// async global->LDS, 16B per lane; LDS dest = wave-uniform base + lane*16
typedef const __attribute__((address_space(1))) unsigned int* gas_ptr;
typedef __attribute__((address_space(3))) unsigned int* las_ptr;
__device__ __forceinline__ void gload_lds16(const unsigned short* g, unsigned short* l) {
  __builtin_amdgcn_global_load_lds((gas_ptr)(const void*)g, (las_ptr)(void*)l, 16, 0, 0);
}

// ---------- dtype detection: flag=1 if input is bf16, 0 if fp32 ----------
__global__ __launch_bounds__(256) void detect_k(const unsigned short* __restrict__ h,
                                                int* __restrict__ flag) {
  __shared__ int s[256];
  int cnt = 0;
  for (int i = threadIdx.x; i < 4096; i += 256) {
    unsigned short u = h[2 * i];
    int e = (u >> 7) & 0xFF;
    if ((e >= 96 && e <= 140) || u == 0) cnt++;
  }
  s[threadIdx.x] = cnt;
  __syncthreads();
  for (int o = 128; o > 0; o >>= 1) {
    if (threadIdx.x < o) s[threadIdx.x] += s[threadIdx.x + o];
    __syncthreads();
  }
  if (threadIdx.x == 0) *flag = (s[0] >= 3600) ? 1 : 0;
}

// ---------- hidden cvt (vectorized: float4 in, ushort8 out) ----------
__global__ __launch_bounds__(256) void cvt_hidden_k(const void* __restrict__ src,
                                                    unsigned short* __restrict__ dst, int n8,
                                                    const int* __restrict__ flag) {
  if (*flag) return;  // bf16 input: GEMM reads d_in[0] directly
  const float4* s = (const float4*)src;
  for (int i = blockIdx.x * 256 + threadIdx.x; i < n8; i += gridDim.x * 256) {
    float4 a = s[2 * i], b = s[2 * i + 1];
    us8 o;
    o[0] = f2bf(a.x); o[1] = f2bf(a.y); o[2] = f2bf(a.z); o[3] = f2bf(a.w);
    o[4] = f2bf(b.x); o[5] = f2bf(b.y); o[6] = f2bf(b.z); o[7] = f2bf(b.w);
    *(us8*)&dst[8 * i] = o;
  }
}

// ---------- fused weight transpose+convert (ushort4 stores) ----------
__global__ __launch_bounds__(256) void transpose_w2_k(const void* __restrict__ w_qkv,
                                                      const void* __restrict__ w_proj,
                                                      unsigned short* __restrict__ dst_qkv,
                                                      unsigned short* __restrict__ dst_proj,
                                                      const int* __restrict__ flag) {
  __shared__ unsigned short tile[32][33];
  const int f = *flag;
  int bid = blockIdx.x;
  const void* src;
  unsigned short* dst;
  int R = 2048, C, cx, cy;
  if (bid < 12288) {
    src = w_qkv; dst = dst_qkv; C = 6144; cx = bid % 192; cy = bid / 192;
  } else {
    bid -= 12288;
    src = w_proj; dst = dst_proj; C = 2048; cx = bid % 64; cy = bid / 64;
  }
  const int x = threadIdx.x & 31;
  const int y = threadIdx.x >> 5;  // 0..7
  const int r0 = cy * 32, c0 = cx * 32;
#pragma unroll
  for (int i = 0; i < 4; i++) {
    size_t idx = (size_t)(r0 + y + 8 * i) * C + c0 + x;
    tile[y + 8 * i][x] = f ? ((const unsigned short*)src)[idx]
                           : f2bf(((const float*)src)[idx]);
  }
  __syncthreads();
  const int orow = threadIdx.x >> 3;        // 0..31
  const int oc = (threadIdx.x & 7) * 4;     // 0,4,..,28
  us4 v;
  v[0] = tile[oc][orow]; v[1] = tile[oc + 1][orow];
  v[2] = tile[oc + 2][orow]; v[3] = tile[oc + 3][orow];
  *(us4*)&dst[(size_t)(c0 + orow) * R + r0 + oc] = v;
}

// ============================================================================
// QKV GEMM: 256x192 tile, BK=64, 8 waves (4M x 2N, 64x96 each), 3 phases/K-tile.
// Round-3 verified schedule. V columns (n >= 4096) written DIRECTLY TRANSPOSED
// into Vt (us4 of 4 consecutive s); transpose_v_k kernel deleted.
// ============================================================================
__global__ __launch_bounds__(512, 2) void gemm_qkv_k(const unsigned short* __restrict__ A_bf,
                                                     const unsigned short* __restrict__ A_cvt,
                                                     const unsigned short* __restrict__ Bt,
                                                     const void* __restrict__ bias,
                                                     unsigned short* __restrict__ Cout,
                                                     unsigned short* __restrict__ Vt,
                                                     int M, int N, int K,
                                                     const int* __restrict__ flag) {
  __shared__ __attribute__((aligned(16))) unsigned short As[2][256][64];
  __shared__ __attribute__((aligned(16))) unsigned short Bs[2][192][64];
  const int f = *flag;
  const unsigned short* Ap = f ? A_bf : A_cvt;
  const int t = threadIdx.x;
  const int wave = t >> 6, lane = t & 63;
  const int col = lane & 15, quad = lane >> 4;
  const int wm = wave >> 1, wn = wave & 1;  // 4M x 2N; per-wave 64 rows x 96 cols

  // bijective XCD swizzle (nwg = 512, %8 == 0)
  const int nbx = N / 192;
  int wgid = blockIdx.y * nbx + blockIdx.x;
  const int nwg = (M >> 8) * nbx;
  if ((nwg & 7) == 0) {
    const int cpx = nwg >> 3;
    wgid = (wgid & 7) * cpx + (wgid >> 3);
  }
  const int n0 = (wgid % nbx) * 192;
  const int m0 = (wgid / nbx) << 8;

  const int srow = lane >> 3;              // 0..7 within an 8-row group
  const int sx = ((lane & 7) ^ srow) * 8;  // pre-swizzled global k-chunk (shorts)
  const int rsw = col & 7;                 // read-side swizzle key

  const unsigned short* pA = Ap + (size_t)(m0 + wave * 8 + srow) * K + sx;
  const unsigned short* pB = Bt + (size_t)(n0 + wave * 8 + srow) * K + sx;
  const int NT = K >> 6;  // 32

#define STAGE_A(d, q, kt) \
  gload_lds16(pA + (size_t)((q) * 64) * K + (size_t)(kt) * 64, &As[(d)][(q) * 64 + wave * 8][0])
#define STAGE_B(d, q, kt) \
  gload_lds16(pB + (size_t)((q) * 64) * K + (size_t)(kt) * 64, &Bs[(d)][(q) * 64 + wave * 8][0])
#define LDA(d, rf, kk) \
  (*(const bf16x8*)&As[(d)][wm * 64 + (rf) * 16 + col][((((kk) << 2) | quad) ^ rsw) * 8])
#define LDB(d, cf, kk) \
  (*(const bf16x8*)&Bs[(d)][wn * 96 + (cf) * 16 + col][((((kk) << 2) | quad) ^ rsw) * 8])

  const f32x4 fzero = {0.f, 0.f, 0.f, 0.f};
  f32x4 acc[4][6];
#pragma unroll
  for (int i = 0; i < 4; i++)
#pragma unroll
    for (int j = 0; j < 6; j++) acc[i][j] = fzero;

  bf16x8 aA[4][2], aB[4][2];  // ping-pong A fragment sets (static-indexed)

  STAGE_A(0, 0, 0); STAGE_A(0, 1, 0); STAGE_A(0, 2, 0); STAGE_A(0, 3, 0);
  STAGE_B(0, 0, 0); STAGE_B(0, 1, 0); STAGE_B(0, 2, 0);
  STAGE_A(1, 0, 1); STAGE_A(1, 1, 1); STAGE_A(1, 2, 1); STAGE_A(1, 3, 1);
  asm volatile("s_waitcnt vmcnt(4)" ::: "memory");
  __builtin_amdgcn_sched_barrier(0);
  __builtin_amdgcn_s_barrier();

#define BODY(D, U, FIRST, SB, SA, VM2, VM3, PRER, ACUR, ANXT)                              \
  {                                                                                        \
    if (FIRST) {                                                                           \
      _Pragma("unroll") for (int rf = 0; rf < 4; rf++) {                                   \
        ACUR[rf][0] = LDA(D, rf, 0);                                                       \
        ACUR[rf][1] = LDA(D, rf, 1);                                                       \
      }                                                                                    \
    }                                                                                      \
    bf16x8 b01[2][2];                                                                      \
    _Pragma("unroll") for (int c = 0; c < 2; c++) {                                        \
      b01[c][0] = LDB(D, c, 0);                                                            \
      b01[c][1] = LDB(D, c, 1);                                                            \
    }                                                                                      \
    if (SB) { STAGE_B((D) ^ 1, 0, (U) + 1); STAGE_B((D) ^ 1, 1, (U) + 1); }                \
    __builtin_amdgcn_s_barrier();                                                          \
    asm volatile("s_waitcnt lgkmcnt(0)" ::: "memory");                                     \
    __builtin_amdgcn_sched_barrier(0);                                                     \
    __builtin_amdgcn_s_setprio(1);                                                         \
    _Pragma("unroll") for (int rf = 0; rf < 4; rf++)                                       \
      _Pragma("unroll") for (int c = 0; c < 2; c++) {                                      \
        acc[rf][c] = __builtin_amdgcn_mfma_f32_16x16x32_bf16(ACUR[rf][0], b01[c][0], acc[rf][c], 0, 0, 0); \
        acc[rf][c] = __builtin_amdgcn_mfma_f32_16x16x32_bf16(ACUR[rf][1], b01[c][1], acc[rf][c], 0, 0, 0); \
      }                                                                                    \
    __builtin_amdgcn_s_setprio(0);                                                         \
    bf16x8 b23[2][2];                                                                      \
    _Pragma("unroll") for (int c = 0; c < 2; c++) {                                        \
      b23[c][0] = LDB(D, (c) + 2, 0);                                                      \
      b23[c][1] = LDB(D, (c) + 2, 1);                                                      \
    }                                                                                      \
    if (SB) STAGE_B((D) ^ 1, 2, (U) + 1);                                                  \
    if (SA) { STAGE_A(D, 0, (U) + 2); STAGE_A(D, 1, (U) + 2); }                            \
    asm volatile("s_waitcnt " VM2 ::: "memory");                                           \
    __builtin_amdgcn_s_barrier();                                                          \
    asm volatile("s_waitcnt lgkmcnt(0)" ::: "memory");                                     \
    __builtin_amdgcn_sched_barrier(0);                                                     \
    __builtin_amdgcn_s_setprio(1);                                                         \
    _Pragma("unroll") for (int rf = 0; rf < 4; rf++)                                       \
      _Pragma("unroll") for (int c = 0; c < 2; c++) {                                      \
        acc[rf][(c) + 2] = __builtin_amdgcn_mfma_f32_16x16x32_bf16(ACUR[rf][0], b23[c][0], acc[rf][(c) + 2], 0, 0, 0); \
        acc[rf][(c) + 2] = __builtin_amdgcn_mfma_f32_16x16x32_bf16(ACUR[rf][1], b23[c][1], acc[rf][(c) + 2], 0, 0, 0); \
      }                                                                                    \
    __builtin_amdgcn_s_setprio(0);                                                         \
    bf16x8 b45[2][2];                                                                      \
    _Pragma("unroll") for (int c = 0; c < 2; c++) {                                        \
      b45[c][0] = LDB(D, (c) + 4, 0);                                                      \
      b45[c][1] = LDB(D, (c) + 4, 1);                                                      \
    }                                                                                      \
    __builtin_amdgcn_sched_barrier(0); /* pin: b45 issued before pre-reads (lgkm count) */ \
    if (PRER) {                                                                            \
      _Pragma("unroll") for (int rf = 0; rf < 4; rf++) {                                   \
        ANXT[rf][0] = LDA((D) ^ 1, rf, 0);                                                 \
        ANXT[rf][1] = LDA((D) ^ 1, rf, 1);                                                 \
      }                                                                                    \
    }                                                                                      \
    if (SA) { STAGE_A(D, 2, (U) + 2); STAGE_A(D, 3, (U) + 2); }                            \
    asm volatile("s_waitcnt " VM3 ::: "memory");                                           \
    __builtin_amdgcn_s_barrier();                                                          \
    if (PRER) asm volatile("s_waitcnt lgkmcnt(8)" ::: "memory");                           \
    else      asm volatile("s_waitcnt lgkmcnt(0)" ::: "memory");                           \
    __builtin_amdgcn_sched_barrier(0);                                                     \
    __builtin_amdgcn_s_setprio(1);                                                         \
    _Pragma("unroll") for (int rf = 0; rf < 4; rf++)                                       \
      _Pragma("unroll") for (int c = 0; c < 2; c++) {                                      \
        acc[rf][(c) + 4] = __builtin_amdgcn_mfma_f32_16x16x32_bf16(ACUR[rf][0], b45[c][0], acc[rf][(c) + 4], 0, 0, 0); \
        acc[rf][(c) + 4] = __builtin_amdgcn_mfma_f32_16x16x32_bf16(ACUR[rf][1], b45[c][1], acc[rf][(c) + 4], 0, 0, 0); \
      }                                                                                    \
    __builtin_amdgcn_s_setprio(0);                                                         \
  }

  BODY(0, 0, 1, 1, 1, "vmcnt(5)", "vmcnt(4)", 1, aA, aB)
  BODY(1, 1, 0, 1, 1, "vmcnt(5)", "vmcnt(4)", 1, aB, aA)
  for (int u2 = 2; u2 + 3 < NT; u2 += 2) {
    BODY(0, u2, 0, 1, 1, "vmcnt(5)", "vmcnt(4)", 1, aA, aB)
    BODY(1, u2 + 1, 0, 1, 1, "vmcnt(5)", "vmcnt(4)", 1, aB, aA)
  }
  BODY(0, NT - 2, 0, 1, 0, "vmcnt(3)", "vmcnt(0)", 1, aA, aB)
  BODY(1, NT - 1, 0, 0, 0, "vmcnt(0)", "vmcnt(0)", 0, aB, aA)

#undef BODY
#undef STAGE_A
#undef STAGE_B
#undef LDA
#undef LDB

  // epilogue: Q/K -> Cout (row-major); V (n>=4096) -> Vt transposed.
  const int vb = m0 >> 11;        // batch (m0 multiple of 256: never straddles)
  const int vs = (m0 & 2047) + wm * 64 + quad * 4;
#pragma unroll
  for (int cf = 0; cf < 6; cf++) {
    int n = n0 + wn * 96 + cf * 16 + col;
    float bv = f ? bf2f(((const unsigned short*)bias)[n]) : ((const float*)bias)[n];
    if (n < 4096) {
#pragma unroll
      for (int rf = 0; rf < 4; rf++)
#pragma unroll
        for (int r = 0; r < 4; r++) {
          int m = m0 + wm * 64 + rf * 16 + quad * 4 + r;
          Cout[(size_t)m * N + n] = f2bf(acc[rf][cf][r] + bv);
        }
    } else {
      size_t vrow = ((size_t)(vb * 2048 + (n - 4096))) * 2048;
#pragma unroll
      for (int rf = 0; rf < 4; rf++) {
        us4 vv;
#pragma unroll
        for (int r = 0; r < 4; r++) vv[r] = f2bf(acc[rf][cf][r] + bv);
        *(us4*)&Vt[vrow + vs + rf * 16] = vv;
      }
    }
  }
}

// ============================================================================
// proj GEMM, 256x128 tile, BK=64, 8 waves, 2 phases/K-tile, grid 256 = 1 round.
// (unchanged)
// ============================================================================
__global__ __launch_bounds__(512, 2) void gemm_proj_k(const unsigned short* __restrict__ A,
                                                      const unsigned short* __restrict__ Bt,
                                                      const void* __restrict__ bias,
                                                      void* __restrict__ Cout,
                                                      int M, int N, int K,
                                                      const int* __restrict__ flag) {
  __shared__ __attribute__((aligned(16))) unsigned short As[2][256][64];
  __shared__ __attribute__((aligned(16))) unsigned short Bs[2][128][64];
  const int f = *flag;
  const int t = threadIdx.x;
  const int wave = t >> 6, lane = t & 63;
  const int col = lane & 15, quad = lane >> 4;
  const int wm = wave >> 1, wn = wave & 1;  // 4M x 2N; per-wave 64 x 64

  const int nbx = N >> 7;
  int wgid = blockIdx.y * nbx + blockIdx.x;
  const int nwg = (M >> 8) * nbx;
  if ((nwg & 7) == 0) {
    const int cpx = nwg >> 3;
    wgid = (wgid & 7) * cpx + (wgid >> 3);
  }
  const int n0 = (wgid % nbx) << 7;
  const int m0 = (wgid / nbx) << 8;

  const int srow = lane >> 3;
  const int sx = ((lane & 7) ^ srow) * 8;
  const int rsw = col & 7;

  const unsigned short* pA = A + (size_t)(m0 + wave * 8 + srow) * K + sx;
  const unsigned short* pB = Bt + (size_t)(n0 + wave * 8 + srow) * K + sx;
  const int NT = K >> 6;  // 32

#define STAGE_A(d, q, kt) \
  gload_lds16(pA + (size_t)((q) * 64) * K + (size_t)(kt) * 64, &As[(d)][(q) * 64 + wave * 8][0])
#define STAGE_B(d, q, kt) \
  gload_lds16(pB + (size_t)((q) * 64) * K + (size_t)(kt) * 64, &Bs[(d)][(q) * 64 + wave * 8][0])
#define LDA(d, rf, kk) \
  (*(const bf16x8*)&As[(d)][wm * 64 + (rf) * 16 + col][((((kk) << 2) | quad) ^ rsw) * 8])
#define LDB(d, cf, kk) \
  (*(const bf16x8*)&Bs[(d)][wn * 64 + (cf) * 16 + col][((((kk) << 2) | quad) ^ rsw) * 8])

  const f32x4 fzero = {0.f, 0.f, 0.f, 0.f};
  f32x4 acc[4][4];
#pragma unroll
  for (int i = 0; i < 4; i++)
#pragma unroll
    for (int j = 0; j < 4; j++) acc[i][j] = fzero;

  bf16x8 aA[4][2], aB[4][2];

  STAGE_A(0, 0, 0); STAGE_A(0, 1, 0); STAGE_A(0, 2, 0); STAGE_A(0, 3, 0);
  STAGE_B(0, 0, 0); STAGE_B(0, 1, 0);
  STAGE_A(1, 0, 1); STAGE_A(1, 1, 1); STAGE_A(1, 2, 1); STAGE_A(1, 3, 1);
  asm volatile("s_waitcnt vmcnt(4)" ::: "memory");
  __builtin_amdgcn_sched_barrier(0);
  __builtin_amdgcn_s_barrier();

#define BODY(D, U, FIRST, SB, SA, VM1, VM2, PRER, ACUR, ANXT)                              \
  {                                                                                        \
    if (FIRST) {                                                                           \
      _Pragma("unroll") for (int rf = 0; rf < 4; rf++) {                                   \
        ACUR[rf][0] = LDA(D, rf, 0);                                                       \
        ACUR[rf][1] = LDA(D, rf, 1);                                                       \
      }                                                                                    \
    }                                                                                      \
    bf16x8 b01[2][2];                                                                      \
    _Pragma("unroll") for (int c = 0; c < 2; c++) {                                        \
      b01[c][0] = LDB(D, c, 0);                                                            \
      b01[c][1] = LDB(D, c, 1);                                                            \
    }                                                                                      \
    if (SB) { STAGE_B((D) ^ 1, 0, (U) + 1); STAGE_B((D) ^ 1, 1, (U) + 1); }                \
    asm volatile("s_waitcnt " VM1 ::: "memory");                                           \
    __builtin_amdgcn_s_barrier();                                                          \
    asm volatile("s_waitcnt lgkmcnt(0)" ::: "memory");                                     \
    __builtin_amdgcn_sched_barrier(0);                                                     \
    __builtin_amdgcn_s_setprio(1);                                                         \
    _Pragma("unroll") for (int rf = 0; rf < 4; rf++)                                       \
      _Pragma("unroll") for (int c = 0; c < 2; c++) {                                      \
        acc[rf][c] = __builtin_amdgcn_mfma_f32_16x16x32_bf16(ACUR[rf][0], b01[c][0], acc[rf][c], 0, 0, 0); \
        acc[rf][c] = __builtin_amdgcn_mfma_f32_16x16x32_bf16(ACUR[rf][1], b01[c][1], acc[rf][c], 0, 0, 0); \
      }                                                                                    \
    __builtin_amdgcn_s_setprio(0);                                                         \
    bf16x8 b23[2][2];                                                                      \
    _Pragma("unroll") for (int c = 0; c < 2; c++) {                                        \
      b23[c][0] = LDB(D, (c) + 2, 0);                                                      \
      b23[c][1] = LDB(D, (c) + 2, 1);                                                      \
    }                                                                                      \
    __builtin_amdgcn_sched_barrier(0); /* pin: b23 before pre-reads */                     \
    if (PRER) {                                                                            \
      _Pragma("unroll") for (int rf = 0; rf < 4; rf++) {                                   \
        ANXT[rf][0] = LDA((D) ^ 1, rf, 0);                                                 \
        ANXT[rf][1] = LDA((D) ^ 1, rf, 1);                                                 \
      }                                                                                    \
    }                                                                                      \
    if (SA) { STAGE_A(D, 0, (U) + 2); STAGE_A(D, 1, (U) + 2);                              \
              STAGE_A(D, 2, (U) + 2); STAGE_A(D, 3, (U) + 2); }                            \
    asm volatile("s_waitcnt " VM2 ::: "memory");                                           \
    __builtin_amdgcn_s_barrier();                                                          \
    if (PRER) asm volatile("s_waitcnt lgkmcnt(8)" ::: "memory");                           \
    else      asm volatile("s_waitcnt lgkmcnt(0)" ::: "memory");                           \
    __builtin_amdgcn_sched_barrier(0);                                                     \
    __builtin_amdgcn_s_setprio(1);                                                         \
    _Pragma("unroll") for (int rf = 0; rf < 4; rf++)                                       \
      _Pragma("unroll") for (int c = 0; c < 2; c++) {                                      \
        acc[rf][(c) + 2] = __builtin_amdgcn_mfma_f32_16x16x32_bf16(ACUR[rf][0], b23[c][0], acc[rf][(c) + 2], 0, 0, 0); \
        acc[rf][(c) + 2] = __builtin_amdgcn_mfma_f32_16x16x32_bf16(ACUR[rf][1], b23[c][1], acc[rf][(c) + 2], 0, 0, 0); \
      }                                                                                    \
    __builtin_amdgcn_s_setprio(0);                                                         \
  }

  BODY(0, 0, 1, 1, 1, "vmcnt(2)", "vmcnt(4)", 1, aA, aB)
  BODY(1, 1, 0, 1, 1, "vmcnt(2)", "vmcnt(4)", 1, aB, aA)
  for (int u2 = 2; u2 + 3 < NT; u2 += 2) {
    BODY(0, u2, 0, 1, 1, "vmcnt(2)", "vmcnt(4)", 1, aA, aB)
    BODY(1, u2 + 1, 0, 1, 1, "vmcnt(2)", "vmcnt(4)", 1, aB, aA)
  }
  BODY(0, NT - 2, 0, 1, 0, "vmcnt(2)", "vmcnt(0)", 1, aA, aB)
  BODY(1, NT - 1, 0, 0, 0, "vmcnt(0)", "vmcnt(0)", 0, aB, aA)

#undef BODY
#undef STAGE_A
#undef STAGE_B
#undef LDA
#undef LDB

  const int f32o = (f == 0);
#pragma unroll
  for (int cf = 0; cf < 4; cf++) {
    int n = n0 + wn * 64 + cf * 16 + col;
    float bv = f ? bf2f(((const unsigned short*)bias)[n]) : ((const float*)bias)[n];
#pragma unroll
    for (int rf = 0; rf < 4; rf++)
#pragma unroll
      for (int r = 0; r < 4; r++) {
        int m = m0 + wm * 64 + rf * 16 + quad * 4 + r;
        float v = acc[rf][cf][r] + bv;
        if (f32o) ((float*)Cout)[(size_t)m * N + n] = v;
        else      ((unsigned short*)Cout)[(size_t)m * N + n] = f2bf(v);
      }
  }
}

// ---------- flash attention (causal), paired q-tiles ----------
// REVERTED to round-5 structure (the one measured inside the 378.9 total):
// K/V double-buffered in LDS, ONE __syncthreads per kt iteration, 1-deep
// prefetch (loads at top of iter, ds_write after PV), cvt_pk softmax,
// direct blockIdx.x mapping. Round-6 lesson: 2-deep prefetch + raw-barrier
// fences + XCD remap cost +30 us (latency-bound regime; compiler schedule
// of the simple structure wins — same as round-4 GEMM lesson).
#define ATT_SC2 0.1275174367076458f  // (1/sqrt(128)) * log2(e)
__global__ __launch_bounds__(256) void attn_k(const unsigned short* __restrict__ qkv,
                                              const unsigned short* __restrict__ Vt,
                                              unsigned short* __restrict__ O) {
  __shared__ __attribute__((aligned(16))) unsigned short Ks[2][64][136];  // [key][d]
  __shared__ __attribute__((aligned(16))) unsigned short Vs[2][128][72];  // V^T: [d][key]
  __shared__ __attribute__((aligned(16))) unsigned short Ps[4][16][72];
  const int t = threadIdx.x;
  const int wave = t >> 6, lane = t & 63;
  const int col = lane & 15, quad = lane >> 4;
  const int h = blockIdx.y, b = blockIdx.z;
  const size_t base = (size_t)b * 2048 * 6144;
  const size_t vbase = ((size_t)(b * 16 + h)) * 128 * 2048;
  const int hcol = h * 128;

  const int kr = t >> 2;
  const int kc = (t & 3) * 8;
  const int vr = t >> 1;
  const int vc = (t & 1) * 32;

  const f32x4 fzero = {0.f, 0.f, 0.f, 0.f};

  for (int pass = 0; pass < 2; pass++) {
    const int qt = pass ? (int)blockIdx.x : 31 - (int)blockIdx.x;

    bf16x8 qf[4];
    {
      size_t qrow = base + (size_t)(qt * 64 + wave * 16 + col) * 6144 + hcol;
#pragma unroll
      for (int ks = 0; ks < 4; ks++)
        qf[ks] = *(const bf16x8*)&qkv[qrow + ks * 32 + quad * 8];
    }

    f32x4 o[8];
#pragma unroll
    for (int i = 0; i < 8; i++) o[i] = fzero;
    float l_i[4] = {0.f, 0.f, 0.f, 0.f};

    __syncthreads();  // guard LDS (both buffers) vs previous pass readers
    {
      size_t grow = base + (size_t)kr * 6144 + 2048 + hcol;
#pragma unroll
      for (int p = 0; p < 4; p++)
        *(bf16x8*)&Ks[0][kr][kc + p * 32] = *(const bf16x8*)&qkv[grow + kc + p * 32];
      size_t vrow = vbase + (size_t)vr * 2048;
#pragma unroll
      for (int c = 0; c < 4; c++)
        *(bf16x8*)&Vs[0][vr][vc + c * 8] = *(const bf16x8*)&Vt[vrow + vc + c * 8];
    }
    __syncthreads();
    int dbf = 0;

    for (int kt = 0; kt <= qt; kt++) {
      bf16x8 kreg[4], vreg[4];
      const bool pf = (kt < qt);
      if (pf) {
        size_t grow = base + (size_t)((kt + 1) * 64 + kr) * 6144 + 2048 + hcol;
#pragma unroll
        for (int p = 0; p < 4; p++)
          kreg[p] = *(const bf16x8*)&qkv[grow + kc + p * 32];
        size_t vrow = vbase + (size_t)vr * 2048 + (kt + 1) * 64;
#pragma unroll
        for (int c = 0; c < 4; c++)
          vreg[c] = *(const bf16x8*)&Vt[vrow + vc + c * 8];
      }

      f32x4 sc[4];
      __builtin_amdgcn_s_setprio(1);
#pragma unroll
      for (int nb = 0; nb < 4; nb++) {
        f32x4 s = fzero;
#pragma unroll
        for (int ks = 0; ks < 4; ks++) {
          bf16x8 kf = *(const bf16x8*)&Ks[dbf][nb * 16 + col][ks * 32 + quad * 8];
          s = __builtin_amdgcn_mfma_f32_16x16x32_bf16(qf[ks], kf, s, 0, 0, 0);
        }
        sc[nb] = s;
      }
      __builtin_amdgcn_s_setprio(0);

      const bool diag = (kt == qt);
#pragma unroll
      for (int nb = 0; nb < 4; nb++) {
        int kl = nb * 16 + col;
        float p0, p1, p2, p3;
        {
          float s0 = sc[nb][0], s1 = sc[nb][1], s2 = sc[nb][2], s3 = sc[nb][3];
          if (diag) {
            int qrow = wave * 16 + quad * 4;
            if (kl > qrow + 0) s0 = -1e30f;
            if (kl > qrow + 1) s1 = -1e30f;
            if (kl > qrow + 2) s2 = -1e30f;
            if (kl > qrow + 3) s3 = -1e30f;
          }
          p0 = exp2f(s0 * ATT_SC2); p1 = exp2f(s1 * ATT_SC2);
          p2 = exp2f(s2 * ATT_SC2); p3 = exp2f(s3 * ATT_SC2);
          l_i[0] += p0; l_i[1] += p1; l_i[2] += p2; l_i[3] += p3;
        }
        unsigned int w01 = cvtpk_bf16(p0, p1);
        unsigned int w23 = cvtpk_bf16(p2, p3);
        unsigned short* pb = &Ps[wave][quad * 4][nb * 16 + col];
        pb[0]   = (unsigned short)w01;
        pb[72]  = (unsigned short)(w01 >> 16);
        pb[144] = (unsigned short)w23;
        pb[216] = (unsigned short)(w23 >> 16);
      }
      bf16x8 pfr[2];
#pragma unroll
      for (int ks2 = 0; ks2 < 2; ks2++)
        pfr[ks2] = *(const bf16x8*)&Ps[wave][col][ks2 * 32 + quad * 8];
      __builtin_amdgcn_s_setprio(1);
#pragma unroll
      for (int nbo = 0; nbo < 8; nbo++)
#pragma unroll
        for (int ks2 = 0; ks2 < 2; ks2++) {
          bf16x8 vf = *(const bf16x8*)&Vs[dbf][nbo * 16 + col][ks2 * 32 + quad * 8];
          o[nbo] = __builtin_amdgcn_mfma_f32_16x16x32_bf16(pfr[ks2], vf, o[nbo], 0, 0, 0);
        }
      __builtin_amdgcn_s_setprio(0);

      if (pf) {
#pragma unroll
        for (int p = 0; p < 4; p++)
          *(bf16x8*)&Ks[dbf ^ 1][kr][kc + p * 32] = kreg[p];
#pragma unroll
        for (int c = 0; c < 4; c++)
          *(bf16x8*)&Vs[dbf ^ 1][vr][vc + c * 8] = vreg[c];
      }
      __syncthreads();
      dbf ^= 1;
    }

#pragma unroll
    for (int r = 0; r < 4; r++) {
#pragma unroll
      for (int off = 1; off < 16; off <<= 1)
        l_i[r] += __shfl_xor(l_i[r], off, 64);
      l_i[r] = 1.0f / l_i[r];
    }

#pragma unroll
    for (int nbo = 0; nbo < 8; nbo++)
#pragma unroll
      for (int r = 0; r < 4; r++) {
        int m = qt * 64 + wave * 16 + quad * 4 + r;
        O[((size_t)b * 2048 + m) * 2048 + hcol + nbo * 16 + col] = f2bf(o[nbo][r] * l_i[r]);
      }
  }
}

// ---------- launch ----------
extern "C" void kernel_launch(void* const* d_in, const int* in_sizes, int n_in,
                              void* d_out, int out_size, void* d_ws, size_t ws_size,
                              hipStream_t stream) {
  (void)in_sizes; (void)n_in; (void)out_size; (void)ws_size;
  int* flag = (int*)d_ws;
  unsigned short* wsu = (unsigned short*)d_ws + 128;
  unsigned short* Wt_qkv    = wsu;                                  // 6144*2048
  unsigned short* Wt_proj   = Wt_qkv + (size_t)6144 * 2048;         // 2048*2048
  unsigned short* QKV       = Wt_proj + (size_t)2048 * 2048;        // 4096*6144
  unsigned short* hidden_bf = QKV + (size_t)4096 * 6144;            // 4096*2048
  unsigned short* Obuf      = Wt_qkv;     // alias: dead after QKV gemm
  unsigned short* Vt        = hidden_bf + (size_t)4096 * 2048;      // 32*128*2048

  detect_k<<<1, 256, 0, stream>>>((const unsigned short*)d_in[0], flag);
  cvt_hidden_k<<<2048, 256, 0, stream>>>(d_in[0], hidden_bf, (4096 * 2048) / 8, flag);
  transpose_w2_k<<<16384, 256, 0, stream>>>(d_in[1], d_in[3], Wt_qkv, Wt_proj, flag);
  // QKV GEMM: 256x192 tile, grid 32x16 = 512 blocks; V written direct to Vt
  gemm_qkv_k<<<dim3(32, 16), 512, 0, stream>>>((const unsigned short*)d_in[0], hidden_bf,
                                               Wt_qkv, d_in[2], QKV, Vt,
                                               4096, 6144, 2048, flag);
  attn_k<<<dim3(16, 16, 2), 256, 0, stream>>>(QKV, Vt, Obuf);
  // proj GEMM: 256x128 tile, grid 16x16 = 256 blocks = exactly 1 round
  gemm_proj_k<<<dim3(16, 16), 512, 0, stream>>>(Obuf, Wt_proj, d_in[4], d_out,
                                                4096, 2048, 2048, flag);
}